// Round 9
// baseline (586.880 us; speedup 1.0000x reference)
//
#include <hip/hip_runtime.h>
#include <hip/hip_bf16.h>
#include <stdint.h>

using bf16x8 = __attribute__((ext_vector_type(8))) __bf16;
using bf16x4 = __attribute__((ext_vector_type(4))) __bf16;
using f32x4  = __attribute__((ext_vector_type(4))) float;

typedef const uint32_t __attribute__((address_space(1)))* gas_ptr;
typedef uint32_t __attribute__((address_space(3)))* las_ptr;

__device__ __forceinline__ void load_lds16(const void* g, void* l) {
    __builtin_amdgcn_global_load_lds((gas_ptr)g, (las_ptr)l, 16, 0, 0);
}

// cprelu post-normalization constants (PRELU_INIT = 0.25)
#define PM  0.29920671030107454f
#define PIS 1.5046096f
#define RHALF 0.70710678118654752f

#define MFMA __builtin_amdgcn_mfma_f32_16x16x32_bf16

// ---------------------------------------------------------------- k_prep
__global__ __launch_bounds__(256) void k_prep(const float* __restrict__ w1,
                                              const float* __restrict__ w2,
                                              const float* __restrict__ wm,
                                              const float* __restrict__ wsw,
                                              __bf16* __restrict__ W1p,
                                              __bf16* __restrict__ W2p,
                                              __bf16* __restrict__ WMp,
                                              __bf16* __restrict__ WSp)
{
    const int id = blockIdx.x * 256 + threadIdx.x;
    const int stride = gridDim.x * 256;
    for (int i = id; i < 96 * 64; i += stride) {
        int oc = i >> 6, ic = i & 63;
        W1p[i] = (__bf16)((oc < 83) ? w1[oc * 64 + ic] : 0.f);
    }
    for (int i = id; i < 112 * 96; i += stride) {
        int oc = i / 96, ic = i % 96;
        W2p[i] = (__bf16)((oc < 102 && ic < 83) ? w2[oc * 83 + ic] : 0.f);
    }
    for (int i = id; i < 128 * 128; i += stride) {
        int oc = i >> 7, ic = i & 127;
        WMp[i] = (__bf16)((ic < 102) ? wm[oc * 102 + ic] : 0.f);
    }
    for (int i = id; i < 128 * 64; i += stride) {
        WSp[i] = (__bf16)wsw[i];
    }
}

// ---------------------------------------------------------------- k_cc
// Fused k_conv (4096 blocks) + k_chain (2048 blocks), interleaved 2:1.
// FROZEN from r8 for clean attribution.
__global__ __launch_bounds__(256) void k_cc(
    // conv args
    const float* __restrict__ conn, __bf16* __restrict__ cb, size_t rowstride,
    int* __restrict__ cnt, int* __restrict__ idx,
    // chain args
    const float* __restrict__ x,
    const float* __restrict__ b1, const float* __restrict__ p1,
    const float* __restrict__ b2, const float* __restrict__ p2,
    const float* __restrict__ bm, const float* __restrict__ bs,
    const __bf16* __restrict__ W1p, const __bf16* __restrict__ W2p,
    const __bf16* __restrict__ WMp, const __bf16* __restrict__ WSp,
    __bf16* __restrict__ h3, __bf16* __restrict__ s_t)
{
    __shared__ __align__(16) char pool[38528];
    const int t = threadIdx.x;
    const int bx = blockIdx.x;
    const int r3 = bx % 3;
    const int g  = bx / 3;

    if (r3 < 2) {
        // ------------------------------------------------ conv path
        const int o = 2 * g + r3;              // 0..4095
        float* wmax = (float*)pool;            // 16 B
        int*   scnt = (int*)(pool + 16);
        const float* row = conn + (size_t)o * 8192;
        float4 v[8];
        float m = -1e30f;
#pragma unroll
        for (int q = 0; q < 8; q++) {
            v[q] = *(const float4*)(row + (size_t)(q * 256 + t) * 4);
            m = fmaxf(m, fmaxf(fmaxf(v[q].x, v[q].y), fmaxf(v[q].z, v[q].w)));
        }
        __syncthreads();   // all reads drained before in-place overwrite
        __bf16* drow = cb + (size_t)o * rowstride;
#pragma unroll
        for (int q = 0; q < 8; q++) {
            bf16x4 w;
            w[0] = (__bf16)v[q].x; w[1] = (__bf16)v[q].y;
            w[2] = (__bf16)v[q].z; w[3] = (__bf16)v[q].w;
            *(bf16x4*)(drow + (size_t)(q * 256 + t) * 4) = w;
        }
#pragma unroll
        for (int off = 32; off > 0; off >>= 1) m = fmaxf(m, __shfl_down(m, off, 64));
        if ((t & 63) == 0) wmax[t >> 6] = m;
        if (t == 0) *scnt = 0;
        __syncthreads();
        const float rmax = fmaxf(fmaxf(wmax[0], wmax[1]), fmaxf(wmax[2], wmax[3]));
#pragma unroll
        for (int q = 0; q < 8; q++) {
            float vv[4] = {v[q].x, v[q].y, v[q].z, v[q].w};
#pragma unroll
            for (int e = 0; e < 4; e++) {
                if (vv[e] >= rmax) {
                    int p = atomicAdd(scnt, 1);
                    if (p < 16) idx[o * 16 + p] = (q * 256 + t) * 4 + e;
                }
            }
        }
        __syncthreads();
        if (t == 0) cnt[o] = *scnt < 16 ? *scnt : 16;
        return;
    }

    // ---------------------------------------------------- chain path
    const int b  = g >> 7;                 // 0..15
    const int p0 = (g & 127) * 64;         // 0..8128
    __bf16* buf0 = (__bf16*)pool;          // 64*136 = 17408 B
    __bf16* un   = (__bf16*)(pool + 17408);// 128*72 = 18432 B
    float*  bl   = (float*)(pool + 35840); // 672 floats = 2688 B
    __bf16* H1t  = un;                     // 64 x 104
    __bf16* OutT = un;                     // 128 x 72
    float* b1l = bl;       float* p1l = bl + 96;
    float* b2l = bl + 192; float* p2l = bl + 304;
    float* bml = bl + 416; float* bsl = bl + 544;

    const int lane = t & 63, wid = t >> 6;

    for (int i = t; i < 96; i += 256)  { b1l[i] = (i < 83)  ? b1[i] : 0.f; p1l[i] = (i < 83)  ? p1[i] : 0.f; }
    for (int i = t; i < 112; i += 256) { b2l[i] = (i < 102) ? b2[i] : 0.f; p2l[i] = (i < 102) ? p2[i] : 0.f; }
    for (int i = t; i < 128; i += 256) { bml[i] = bm[i]; bsl[i] = bs[i]; }

    {
        // vectorized x staging: float4 along positions, transpose into LDS
        const int pg = (t & 15) * 4;        // position base 0..60
        const int c0 = t >> 4;              // 0..15
#pragma unroll
        for (int it = 0; it < 4; it++) {
            int c = it * 16 + c0;
            float4 xv = *(const float4*)(x + ((size_t)b * 64 + c) * 8192 + p0 + pg);
            buf0[(pg + 0) * 72 + c] = (__bf16)xv.x;
            buf0[(pg + 1) * 72 + c] = (__bf16)xv.y;
            buf0[(pg + 2) * 72 + c] = (__bf16)xv.z;
            buf0[(pg + 3) * 72 + c] = (__bf16)xv.w;
        }
    }
    __syncthreads();

    const int quad4 = (lane >> 4) << 2;
    const int l15 = lane & 15;
    const int kg  = (lane >> 4) << 3;
    const int nt  = wid;                   // wave-owned column tile
    const int pos = nt * 16 + l15;

    // X fragment (K=64): loaded once, reused by S (8 mt) and H1 (6 mt)
    bf16x8 xb0, xb1;
    {
        const __bf16* bp = buf0 + pos * 72 + kg;
        xb0 = *(const bf16x8*)(bp);
        xb1 = *(const bf16x8*)(bp + 32);
    }

    // shortcut S = WS*X + bs -> direct global store
#pragma unroll
    for (int mt = 0; mt < 8; mt++) {
        const __bf16* wp = WSp + (mt * 16 + l15) * 64 + kg;
        f32x4 a = {0.f, 0.f, 0.f, 0.f};
        a = MFMA(*(const bf16x8*)(wp),      xb0, a, 0, 0, 0);
        a = MFMA(*(const bf16x8*)(wp + 32), xb1, a, 0, 0, 0);
        int ocb = mt * 16 + quad4;
        bf16x4 ov;
#pragma unroll
        for (int r = 0; r < 4; r++) ov[r] = (__bf16)(a[r] + bsl[ocb + r]);
        *(bf16x4*)(s_t + ((size_t)b * 8192 + p0 + pos) * 128 + ocb) = ov;
    }

    // H1 = cprelu(W1*X + b1) -> H1t
#pragma unroll
    for (int mt = 0; mt < 6; mt++) {
        const __bf16* wp = W1p + (mt * 16 + l15) * 64 + kg;
        f32x4 a = {0.f, 0.f, 0.f, 0.f};
        a = MFMA(*(const bf16x8*)(wp),      xb0, a, 0, 0, 0);
        a = MFMA(*(const bf16x8*)(wp + 32), xb1, a, 0, 0, 0);
        int ocb = mt * 16 + quad4;
        bf16x4 ov;
#pragma unroll
        for (int r = 0; r < 4; r++) {
            float v = a[r] + b1l[ocb + r];
            v = (v >= 0.f) ? v : v * p1l[ocb + r];
            ov[r] = (__bf16)((v - PM) * PIS);
        }
        *(bf16x4*)(&H1t[pos * 104 + ocb]) = ov;
    }
    __syncthreads();

    // H2 = cprelu(W2*H1 + b2) -> buf0 (Xt dead); H1 fragment loaded once
    {
        bf16x8 hb[3];
        const __bf16* bp = H1t + pos * 104 + kg;
#pragma unroll
        for (int ks = 0; ks < 3; ks++) hb[ks] = *(const bf16x8*)(bp + ks * 32);
#pragma unroll
        for (int mt = 0; mt < 7; mt++) {
            const __bf16* wp = W2p + (mt * 16 + l15) * 96 + kg;
            f32x4 a = {0.f, 0.f, 0.f, 0.f};
#pragma unroll
            for (int ks = 0; ks < 3; ks++)
                a = MFMA(*(const bf16x8*)(wp + ks * 32), hb[ks], a, 0, 0, 0);
            int ocb = mt * 16 + quad4;
            bf16x4 ov;
#pragma unroll
            for (int r = 0; r < 4; r++) {
                float v = a[r] + b2l[ocb + r];
                v = (v >= 0.f) ? v : v * p2l[ocb + r];
                ov[r] = (__bf16)((v - PM) * PIS);
            }
            *(bf16x4*)(&buf0[pos * 136 + ocb]) = ov;
        }
    }
    // zero H2 pad channels 112..127
    for (int i = t; i < 64 * 16; i += 256) {
        int pp = i >> 4, c = 112 + (i & 15);
        buf0[pp * 136 + c] = (__bf16)0.f;
    }
    __syncthreads();   // H1t reads done before OutT overwrites region

    // H3 = WM*H2 + bm -> OutT[ch][pos]; H2 fragment loaded once
    {
        bf16x8 h2b[4];
        const __bf16* bp = buf0 + pos * 136 + kg;
#pragma unroll
        for (int ks = 0; ks < 4; ks++) h2b[ks] = *(const bf16x8*)(bp + ks * 32);
#pragma unroll
        for (int mt = 0; mt < 8; mt++) {
            const __bf16* wp = WMp + (mt * 16 + l15) * 128 + kg;
            f32x4 a = {0.f, 0.f, 0.f, 0.f};
#pragma unroll
            for (int ks = 0; ks < 4; ks++)
                a = MFMA(*(const bf16x8*)(wp + ks * 32), h2b[ks], a, 0, 0, 0);
            int ocb = mt * 16 + quad4;
#pragma unroll
            for (int r = 0; r < 4; r++)
                OutT[(ocb + r) * 72 + pos] = (__bf16)(a[r] + bml[ocb + r]);
        }
    }
    __syncthreads();

    // coalesced OutT -> h3 (bf16x8 per lane, 128B per channel row)
#pragma unroll
    for (int it = 0; it < 4; it++) {
        int lin = it * 256 + t;       // 0..1023
        int ch = lin >> 3, pc = lin & 7;
        bf16x8 v = *(const bf16x8*)(OutT + ch * 72 + pc * 8);
        *(bf16x8*)(h3 + ((size_t)b * 128 + ch) * 8192 + p0 + pc * 8) = v;
    }
}

// ---------------------------------------------------------------- k_gemm
// out[2048,4096] = combine(A[2048,8192](bf16) x B[4096,bstride](bf16)).
// K-loop byte-identical to r6 (measured 178-184 us three times). R9 change:
// the combine epilogue runs in TWO 64-column passes with sp[64][129] f32
// (33 KB) instead of one sp[128][129] pass (66 KB). Static LDS drops
// 66560 -> 33536 B -> 4 blocks/CU (16 waves/CU) -- the r0 economics that
// measured 907 TF. f32 gather precision kept; loop untouched.
// XOR swizzle: 16B chunk (row, c) of a 64-elem row stored at c ^ (row & 7).
__global__ __launch_bounds__(256, 4) void k_gemm(const __bf16* __restrict__ A,
                                                 const __bf16* __restrict__ B,
                                                 size_t bstride,
                                                 float* __restrict__ out,
                                                 const __bf16* __restrict__ s_t,
                                                 const int* __restrict__ idx,
                                                 const int* __restrict__ cnt,
                                                 const float* __restrict__ p3)
{
    __shared__ __align__(16) char pool[33536];
    __bf16* la = (__bf16*)pool;              // 128*64 bf16 = 16384 B
    __bf16* lb = (__bf16*)(pool + 16384);    // 128*64 bf16 = 16384 B
    float*  sp = (float*)pool;               // [64][129] = 33024 B (after loop)
    float* p3l = (float*)(pool + 33024);     // 512 B (outside la/lb? no: outside sp)

    const int t = threadIdx.x;
    const int lane = t & 63;
    const int wid = t >> 6;
    const int tMi = blockIdx.y;              // batch 0..15
    const int tM = tMi * 128;
    const int tN = blockIdx.x * 128;
    const int wm2 = (wid & 1) * 64;
    const int wn2 = (wid >> 1) * 64;

    f32x4 acc[4][4];
    const f32x4 zero = {0.f, 0.f, 0.f, 0.f};
#pragma unroll
    for (int i = 0; i < 4; i++)
#pragma unroll
        for (int j = 0; j < 4; j++) acc[i][j] = zero;

    // staging: 4 issues per matrix; issue i covers rows i*32..i*32+31
    const int tr = t >> 3;                    // 0..31
    const int sc = (t & 7) ^ (tr & 7);        // swizzled global chunk
    const __bf16* pA[4];
    const __bf16* pB[4];
#pragma unroll
    for (int i = 0; i < 4; i++) {
        pA[i] = A + (size_t)(tM + i * 32 + tr) * 8192 + sc * 8;
        pB[i] = B + (size_t)(tN + i * 32 + tr) * bstride + sc * 8;
    }

    const int l15 = lane & 15;
    const int q = lane >> 4;
    int aoff[4], boff[4];
#pragma unroll
    for (int i = 0; i < 4; i++) {
        int row = wm2 + i * 16 + l15;
        aoff[i] = row * 64 + ((q ^ (row & 7)) * 8);
    }
#pragma unroll
    for (int j = 0; j < 4; j++) {
        int row = wn2 + j * 16 + l15;
        boff[j] = row * 64 + ((q ^ (row & 7)) * 8);
    }

    for (int it = 0; it < 128; it++) {
#pragma unroll
        for (int i = 0; i < 4; i++) load_lds16(pA[i], la + (i * 256 + t) * 8);
#pragma unroll
        for (int i = 0; i < 4; i++) load_lds16(pB[i], lb + (i * 256 + t) * 8);
#pragma unroll
        for (int i = 0; i < 4; i++) { pA[i] += 64; pB[i] += 64; }
        __syncthreads();
#pragma unroll
        for (int ks = 0; ks < 2; ks++) {
            bf16x8 af[4], bfr[4];
#pragma unroll
            for (int i = 0; i < 4; i++) af[i]  = *(const bf16x8*)(la + (aoff[i] ^ (ks << 5)));
#pragma unroll
            for (int j = 0; j < 4; j++) bfr[j] = *(const bf16x8*)(lb + (boff[j] ^ (ks << 5)));
#pragma unroll
            for (int i = 0; i < 4; i++)
#pragma unroll
                for (int j = 0; j < 4; j++)
                    acc[i][j] = MFMA(af[i], bfr[j], acc[i][j], 0, 0, 0);
        }
        __syncthreads();
    }
    // loop ends with __syncthreads(): all LDS reads done, LDS-DMA drained ->
    // pool is safe to reuse.

    if (t < 128) p3l[t] = p3[t];   // p3l region does not overlap sp

    const int quad4 = q * 4;
#pragma unroll
    for (int half = 0; half < 2; half++) {
        __syncthreads();   // prior-half sp reads done before overwrite
        // ---- gather: sp[l][c] = sum_{k<cnt[col]} s_t[b, idx_k, c],
        //      col = tN + half*64 + l, all 256 threads participate
        {
            const int l = t >> 2;                 // col 0..63 within half
            const int part = t & 3;               // channel quarter
            const int col = tN + half * 64 + l;
            const int n = cnt[col];
            const __bf16* base = s_t + ((size_t)tMi * 8192) * 128 + part * 32;
            float* spr = sp + l * 129 + part * 32;
            {
                const __bf16* row = base + (size_t)idx[col * 16] * 128;
#pragma unroll
                for (int j = 0; j < 4; j++) {
                    bf16x8 v = *(const bf16x8*)(row + j * 8);
#pragma unroll
                    for (int u = 0; u < 8; u++) spr[j * 8 + u] = (float)v[u];
                }
            }
            for (int k = 1; k < n; k++) {
                const __bf16* row = base + (size_t)idx[col * 16 + k] * 128;
#pragma unroll
                for (int j = 0; j < 4; j++) {
                    bf16x8 v = *(const bf16x8*)(row + j * 8);
#pragma unroll
                    for (int u = 0; u < 8; u++) spr[j * 8 + u] += (float)v[u];
                }
            }
        }
        __syncthreads();   // sp ready
        // ---- store: waves owning this column half write their tile
        if ((wid >> 1) == half) {
#pragma unroll
            for (int i = 0; i < 4; i++) {
                int gm = tM + wm2 + i * 16 + quad4;
#pragma unroll
                for (int j = 0; j < 4; j++) {
                    int gn = tN + half * 64 + j * 16 + l15;
                    int colL = j * 16 + l15;          // 0..63 within half
#pragma unroll
                    for (int r = 0; r < 4; r++) {
                        int c = wm2 + i * 16 + quad4 + r;   // channel 0..127
                        float v = acc[i][j][r];
                        float pw = p3l[c];
                        float y = (v >= 0.f) ? v : v * pw;
                        y = (y - PM) * PIS;
                        out[(size_t)(gm + r) * 4096 + gn] = sp[colL * 129 + c] * RHALF + y * RHALF;
                    }
                }
            }
        }
    }
}

// ---------------------------------------------------------------- launch
extern "C" void kernel_launch(void* const* d_in, const int* in_sizes, int n_in,
                              void* d_out, int out_size, void* d_ws, size_t ws_size,
                              hipStream_t stream) {
    (void)in_sizes; (void)n_in; (void)out_size;
    const float* x    = (const float*)d_in[0];
    const float* conn = (const float*)d_in[1];
    const float* w1   = (const float*)d_in[2];
    const float* b1   = (const float*)d_in[3];
    const float* p1   = (const float*)d_in[4];
    const float* w2   = (const float*)d_in[5];
    const float* b2   = (const float*)d_in[6];
    const float* p2   = (const float*)d_in[7];
    const float* wm   = (const float*)d_in[8];
    const float* bm   = (const float*)d_in[9];
    const float* p3   = (const float*)d_in[10];
    const float* wsw  = (const float*)d_in[11];
    const float* bs   = (const float*)d_in[12];
    float* out = (float*)d_out;

    char* ws = (char*)d_ws;
    __bf16* h3  = (__bf16*)(ws);                          // 33,554,432 B
    __bf16* s_t = (__bf16*)(ws + 33554432);               // 33,554,432 B
    __bf16* W1p = (__bf16*)(ws + 67108864);               // 12,288
    __bf16* W2p = (__bf16*)(ws + 67108864 + 12288);       // 21,504
    __bf16* WMp = (__bf16*)(ws + 67108864 + 33792);       // 32,768
    __bf16* WSp = (__bf16*)(ws + 67108864 + 66560);       // 16,384
    int* idx = (int*)(ws + 67108864 + 82944);             // 262,144
    int* cnt = (int*)(ws + 67108864 + 82944 + 262144);    // 16,384
    const size_t connb_off = 67108864 + 82944 + 262144 + 16384;   // 67,470,336

    __bf16* connb;
    size_t  cstride;
    if (ws_size >= connb_off + (size_t)4096 * 8192 * 2) {
        connb = (__bf16*)(ws + connb_off);
        cstride = 8192;
    } else {
        connb = (__bf16*)const_cast<float*>(conn);
        cstride = 16384;   // bf16 row packed into first half of its fp32 row
    }

    k_prep<<<32, 256, 0, stream>>>(w1, w2, wm, wsw, W1p, W2p, WMp, WSp);
    k_cc<<<6144, 256, 0, stream>>>(conn, connb, cstride, cnt, idx,
                                   x, b1, p1, b2, p2, bm, bs,
                                   W1p, W2p, WMp, WSp, h3, s_t);
    k_gemm<<<dim3(32, 16), 256, 0, stream>>>(h3, connb, cstride, out, s_t, idx, cnt, p3);
}

// Round 10
// 471.031 us; speedup vs baseline: 1.2459x; 1.2459x over previous
//
#include <hip/hip_runtime.h>
#include <hip/hip_bf16.h>
#include <stdint.h>

using bf16x8 = __attribute__((ext_vector_type(8))) __bf16;
using bf16x4 = __attribute__((ext_vector_type(4))) __bf16;
using f32x4  = __attribute__((ext_vector_type(4))) float;

typedef const uint32_t __attribute__((address_space(1)))* gas_ptr;
typedef uint32_t __attribute__((address_space(3)))* las_ptr;

__device__ __forceinline__ void load_lds16(const void* g, void* l) {
    __builtin_amdgcn_global_load_lds((gas_ptr)g, (las_ptr)l, 16, 0, 0);
}

// cprelu post-normalization constants (PRELU_INIT = 0.25)
#define PM  0.29920671030107454f
#define PIS 1.5046096f
#define RHALF 0.70710678118654752f

#define MFMA __builtin_amdgcn_mfma_f32_16x16x32_bf16

// ---------------------------------------------------------------- k_prep
__global__ __launch_bounds__(256) void k_prep(const float* __restrict__ w1,
                                              const float* __restrict__ w2,
                                              const float* __restrict__ wm,
                                              const float* __restrict__ wsw,
                                              __bf16* __restrict__ W1p,
                                              __bf16* __restrict__ W2p,
                                              __bf16* __restrict__ WMp,
                                              __bf16* __restrict__ WSp)
{
    const int id = blockIdx.x * 256 + threadIdx.x;
    const int stride = gridDim.x * 256;
    for (int i = id; i < 96 * 64; i += stride) {
        int oc = i >> 6, ic = i & 63;
        W1p[i] = (__bf16)((oc < 83) ? w1[oc * 64 + ic] : 0.f);
    }
    for (int i = id; i < 112 * 96; i += stride) {
        int oc = i / 96, ic = i % 96;
        W2p[i] = (__bf16)((oc < 102 && ic < 83) ? w2[oc * 83 + ic] : 0.f);
    }
    for (int i = id; i < 128 * 128; i += stride) {
        int oc = i >> 7, ic = i & 127;
        WMp[i] = (__bf16)((ic < 102) ? wm[oc * 102 + ic] : 0.f);
    }
    for (int i = id; i < 128 * 64; i += stride) {
        WSp[i] = (__bf16)wsw[i];
    }
}

// ---------------------------------------------------------------- k_cc
// Fused k_conv (4096 blocks) + k_chain (2048 blocks), interleaved 2:1.
// FROZEN from r8 for clean attribution.
__global__ __launch_bounds__(256) void k_cc(
    // conv args
    const float* __restrict__ conn, __bf16* __restrict__ cb, size_t rowstride,
    int* __restrict__ cnt, int* __restrict__ idx,
    // chain args
    const float* __restrict__ x,
    const float* __restrict__ b1, const float* __restrict__ p1,
    const float* __restrict__ b2, const float* __restrict__ p2,
    const float* __restrict__ bm, const float* __restrict__ bs,
    const __bf16* __restrict__ W1p, const __bf16* __restrict__ W2p,
    const __bf16* __restrict__ WMp, const __bf16* __restrict__ WSp,
    __bf16* __restrict__ h3, __bf16* __restrict__ s_t)
{
    __shared__ __align__(16) char pool[38528];
    const int t = threadIdx.x;
    const int bx = blockIdx.x;
    const int r3 = bx % 3;
    const int g  = bx / 3;

    if (r3 < 2) {
        // ------------------------------------------------ conv path
        const int o = 2 * g + r3;              // 0..4095
        float* wmax = (float*)pool;            // 16 B
        int*   scnt = (int*)(pool + 16);
        const float* row = conn + (size_t)o * 8192;
        float4 v[8];
        float m = -1e30f;
#pragma unroll
        for (int q = 0; q < 8; q++) {
            v[q] = *(const float4*)(row + (size_t)(q * 256 + t) * 4);
            m = fmaxf(m, fmaxf(fmaxf(v[q].x, v[q].y), fmaxf(v[q].z, v[q].w)));
        }
        __syncthreads();   // all reads drained before in-place overwrite
        __bf16* drow = cb + (size_t)o * rowstride;
#pragma unroll
        for (int q = 0; q < 8; q++) {
            bf16x4 w;
            w[0] = (__bf16)v[q].x; w[1] = (__bf16)v[q].y;
            w[2] = (__bf16)v[q].z; w[3] = (__bf16)v[q].w;
            *(bf16x4*)(drow + (size_t)(q * 256 + t) * 4) = w;
        }
#pragma unroll
        for (int off = 32; off > 0; off >>= 1) m = fmaxf(m, __shfl_down(m, off, 64));
        if ((t & 63) == 0) wmax[t >> 6] = m;
        if (t == 0) *scnt = 0;
        __syncthreads();
        const float rmax = fmaxf(fmaxf(wmax[0], wmax[1]), fmaxf(wmax[2], wmax[3]));
#pragma unroll
        for (int q = 0; q < 8; q++) {
            float vv[4] = {v[q].x, v[q].y, v[q].z, v[q].w};
#pragma unroll
            for (int e = 0; e < 4; e++) {
                if (vv[e] >= rmax) {
                    int p = atomicAdd(scnt, 1);
                    if (p < 16) idx[o * 16 + p] = (q * 256 + t) * 4 + e;
                }
            }
        }
        __syncthreads();
        if (t == 0) cnt[o] = *scnt < 16 ? *scnt : 16;
        return;
    }

    // ---------------------------------------------------- chain path
    const int b  = g >> 7;                 // 0..15
    const int p0 = (g & 127) * 64;         // 0..8128
    __bf16* buf0 = (__bf16*)pool;          // 64*136 = 17408 B
    __bf16* un   = (__bf16*)(pool + 17408);// 128*72 = 18432 B
    float*  bl   = (float*)(pool + 35840); // 672 floats = 2688 B
    __bf16* H1t  = un;                     // 64 x 104
    __bf16* OutT = un;                     // 128 x 72
    float* b1l = bl;       float* p1l = bl + 96;
    float* b2l = bl + 192; float* p2l = bl + 304;
    float* bml = bl + 416; float* bsl = bl + 544;

    const int lane = t & 63, wid = t >> 6;

    for (int i = t; i < 96; i += 256)  { b1l[i] = (i < 83)  ? b1[i] : 0.f; p1l[i] = (i < 83)  ? p1[i] : 0.f; }
    for (int i = t; i < 112; i += 256) { b2l[i] = (i < 102) ? b2[i] : 0.f; p2l[i] = (i < 102) ? p2[i] : 0.f; }
    for (int i = t; i < 128; i += 256) { bml[i] = bm[i]; bsl[i] = bs[i]; }

    {
        // vectorized x staging: float4 along positions, transpose into LDS
        const int pg = (t & 15) * 4;        // position base 0..60
        const int c0 = t >> 4;              // 0..15
#pragma unroll
        for (int it = 0; it < 4; it++) {
            int c = it * 16 + c0;
            float4 xv = *(const float4*)(x + ((size_t)b * 64 + c) * 8192 + p0 + pg);
            buf0[(pg + 0) * 72 + c] = (__bf16)xv.x;
            buf0[(pg + 1) * 72 + c] = (__bf16)xv.y;
            buf0[(pg + 2) * 72 + c] = (__bf16)xv.z;
            buf0[(pg + 3) * 72 + c] = (__bf16)xv.w;
        }
    }
    __syncthreads();

    const int quad4 = (lane >> 4) << 2;
    const int l15 = lane & 15;
    const int kg  = (lane >> 4) << 3;
    const int nt  = wid;                   // wave-owned column tile
    const int pos = nt * 16 + l15;

    // X fragment (K=64): loaded once, reused by S (8 mt) and H1 (6 mt)
    bf16x8 xb0, xb1;
    {
        const __bf16* bp = buf0 + pos * 72 + kg;
        xb0 = *(const bf16x8*)(bp);
        xb1 = *(const bf16x8*)(bp + 32);
    }

    // shortcut S = WS*X + bs -> direct global store
#pragma unroll
    for (int mt = 0; mt < 8; mt++) {
        const __bf16* wp = WSp + (mt * 16 + l15) * 64 + kg;
        f32x4 a = {0.f, 0.f, 0.f, 0.f};
        a = MFMA(*(const bf16x8*)(wp),      xb0, a, 0, 0, 0);
        a = MFMA(*(const bf16x8*)(wp + 32), xb1, a, 0, 0, 0);
        int ocb = mt * 16 + quad4;
        bf16x4 ov;
#pragma unroll
        for (int r = 0; r < 4; r++) ov[r] = (__bf16)(a[r] + bsl[ocb + r]);
        *(bf16x4*)(s_t + ((size_t)b * 8192 + p0 + pos) * 128 + ocb) = ov;
    }

    // H1 = cprelu(W1*X + b1) -> H1t
#pragma unroll
    for (int mt = 0; mt < 6; mt++) {
        const __bf16* wp = W1p + (mt * 16 + l15) * 64 + kg;
        f32x4 a = {0.f, 0.f, 0.f, 0.f};
        a = MFMA(*(const bf16x8*)(wp),      xb0, a, 0, 0, 0);
        a = MFMA(*(const bf16x8*)(wp + 32), xb1, a, 0, 0, 0);
        int ocb = mt * 16 + quad4;
        bf16x4 ov;
#pragma unroll
        for (int r = 0; r < 4; r++) {
            float v = a[r] + b1l[ocb + r];
            v = (v >= 0.f) ? v : v * p1l[ocb + r];
            ov[r] = (__bf16)((v - PM) * PIS);
        }
        *(bf16x4*)(&H1t[pos * 104 + ocb]) = ov;
    }
    __syncthreads();

    // H2 = cprelu(W2*H1 + b2) -> buf0 (Xt dead); H1 fragment loaded once
    {
        bf16x8 hb[3];
        const __bf16* bp = H1t + pos * 104 + kg;
#pragma unroll
        for (int ks = 0; ks < 3; ks++) hb[ks] = *(const bf16x8*)(bp + ks * 32);
#pragma unroll
        for (int mt = 0; mt < 7; mt++) {
            const __bf16* wp = W2p + (mt * 16 + l15) * 96 + kg;
            f32x4 a = {0.f, 0.f, 0.f, 0.f};
#pragma unroll
            for (int ks = 0; ks < 3; ks++)
                a = MFMA(*(const bf16x8*)(wp + ks * 32), hb[ks], a, 0, 0, 0);
            int ocb = mt * 16 + quad4;
            bf16x4 ov;
#pragma unroll
            for (int r = 0; r < 4; r++) {
                float v = a[r] + b2l[ocb + r];
                v = (v >= 0.f) ? v : v * p2l[ocb + r];
                ov[r] = (__bf16)((v - PM) * PIS);
            }
            *(bf16x4*)(&buf0[pos * 136 + ocb]) = ov;
        }
    }
    // zero H2 pad channels 112..127
    for (int i = t; i < 64 * 16; i += 256) {
        int pp = i >> 4, c = 112 + (i & 15);
        buf0[pp * 136 + c] = (__bf16)0.f;
    }
    __syncthreads();   // H1t reads done before OutT overwrites region

    // H3 = WM*H2 + bm -> OutT[ch][pos]; H2 fragment loaded once
    {
        bf16x8 h2b[4];
        const __bf16* bp = buf0 + pos * 136 + kg;
#pragma unroll
        for (int ks = 0; ks < 4; ks++) h2b[ks] = *(const bf16x8*)(bp + ks * 32);
#pragma unroll
        for (int mt = 0; mt < 8; mt++) {
            const __bf16* wp = WMp + (mt * 16 + l15) * 128 + kg;
            f32x4 a = {0.f, 0.f, 0.f, 0.f};
#pragma unroll
            for (int ks = 0; ks < 4; ks++)
                a = MFMA(*(const bf16x8*)(wp + ks * 32), h2b[ks], a, 0, 0, 0);
            int ocb = mt * 16 + quad4;
#pragma unroll
            for (int r = 0; r < 4; r++)
                OutT[(ocb + r) * 72 + pos] = (__bf16)(a[r] + bml[ocb + r]);
        }
    }
    __syncthreads();

    // coalesced OutT -> h3 (bf16x8 per lane, 128B per channel row)
#pragma unroll
    for (int it = 0; it < 4; it++) {
        int lin = it * 256 + t;       // 0..1023
        int ch = lin >> 3, pc = lin & 7;
        bf16x8 v = *(const bf16x8*)(OutT + ch * 72 + pc * 8);
        *(bf16x8*)(h3 + ((size_t)b * 128 + ch) * 8192 + p0 + pc * 8) = v;
    }
}

// ---------------------------------------------------------------- k_gemm
// out[2048,4096] = combine(A[2048,8192](bf16) x B[4096,bstride](bf16)).
// K-loop byte-identical to r6. Two-pass combine epilogue with sp[64][129]
// (static LDS 33.5 KB) so the HARDWARE can co-schedule 4 blocks/CU.
// launch_bounds kept at (256, 2): r9 proved forcing 4 via the 2nd arg makes
// the allocator spill acc to scratch (VGPR 64, WRITE +16MB, dur 308us).
// With (256,2) the r8 build measured 104 VGPR <= 128, which lets the HW
// reach 16 waves/CU on its own now that LDS fits 4x per CU.
// XOR swizzle: 16B chunk (row, c) of a 64-elem row stored at c ^ (row & 7).
__global__ __launch_bounds__(256, 2) void k_gemm(const __bf16* __restrict__ A,
                                                 const __bf16* __restrict__ B,
                                                 size_t bstride,
                                                 float* __restrict__ out,
                                                 const __bf16* __restrict__ s_t,
                                                 const int* __restrict__ idx,
                                                 const int* __restrict__ cnt,
                                                 const float* __restrict__ p3)
{
    __shared__ __align__(16) char pool[33536];
    __bf16* la = (__bf16*)pool;              // 128*64 bf16 = 16384 B
    __bf16* lb = (__bf16*)(pool + 16384);    // 128*64 bf16 = 16384 B
    float*  sp = (float*)pool;               // [64][129] = 33024 B (after loop)
    float* p3l = (float*)(pool + 33024);     // 512 B (outside sp)

    const int t = threadIdx.x;
    const int lane = t & 63;
    const int wid = t >> 6;
    const int tMi = blockIdx.y;              // batch 0..15
    const int tM = tMi * 128;
    const int tN = blockIdx.x * 128;
    const int wm2 = (wid & 1) * 64;
    const int wn2 = (wid >> 1) * 64;

    f32x4 acc[4][4];
    const f32x4 zero = {0.f, 0.f, 0.f, 0.f};
#pragma unroll
    for (int i = 0; i < 4; i++)
#pragma unroll
        for (int j = 0; j < 4; j++) acc[i][j] = zero;

    // staging: 4 issues per matrix; issue i covers rows i*32..i*32+31
    const int tr = t >> 3;                    // 0..31
    const int sc = (t & 7) ^ (tr & 7);        // swizzled global chunk
    const __bf16* pA[4];
    const __bf16* pB[4];
#pragma unroll
    for (int i = 0; i < 4; i++) {
        pA[i] = A + (size_t)(tM + i * 32 + tr) * 8192 + sc * 8;
        pB[i] = B + (size_t)(tN + i * 32 + tr) * bstride + sc * 8;
    }

    const int l15 = lane & 15;
    const int q = lane >> 4;
    int aoff[4], boff[4];
#pragma unroll
    for (int i = 0; i < 4; i++) {
        int row = wm2 + i * 16 + l15;
        aoff[i] = row * 64 + ((q ^ (row & 7)) * 8);
    }
#pragma unroll
    for (int j = 0; j < 4; j++) {
        int row = wn2 + j * 16 + l15;
        boff[j] = row * 64 + ((q ^ (row & 7)) * 8);
    }

    for (int it = 0; it < 128; it++) {
#pragma unroll
        for (int i = 0; i < 4; i++) load_lds16(pA[i], la + (i * 256 + t) * 8);
#pragma unroll
        for (int i = 0; i < 4; i++) load_lds16(pB[i], lb + (i * 256 + t) * 8);
#pragma unroll
        for (int i = 0; i < 4; i++) { pA[i] += 64; pB[i] += 64; }
        __syncthreads();
#pragma unroll
        for (int ks = 0; ks < 2; ks++) {
            bf16x8 af[4], bfr[4];
#pragma unroll
            for (int i = 0; i < 4; i++) af[i]  = *(const bf16x8*)(la + (aoff[i] ^ (ks << 5)));
#pragma unroll
            for (int j = 0; j < 4; j++) bfr[j] = *(const bf16x8*)(lb + (boff[j] ^ (ks << 5)));
#pragma unroll
            for (int i = 0; i < 4; i++)
#pragma unroll
                for (int j = 0; j < 4; j++)
                    acc[i][j] = MFMA(af[i], bfr[j], acc[i][j], 0, 0, 0);
        }
        __syncthreads();
    }
    // loop ends with __syncthreads(): all LDS reads done, LDS-DMA drained ->
    // pool is safe to reuse.

    if (t < 128) p3l[t] = p3[t];   // p3l region does not overlap sp

    const int quad4 = q * 4;
#pragma unroll
    for (int half = 0; half < 2; half++) {
        __syncthreads();   // prior-half sp reads done before overwrite
        // ---- gather: sp[l][c] = sum_{k<cnt[col]} s_t[b, idx_k, c],
        //      col = tN + half*64 + l, all 256 threads participate
        {
            const int l = t >> 2;                 // col 0..63 within half
            const int part = t & 3;               // channel quarter
            const int col = tN + half * 64 + l;
            const int n = cnt[col];
            const __bf16* base = s_t + ((size_t)tMi * 8192) * 128 + part * 32;
            float* spr = sp + l * 129 + part * 32;
            {
                const __bf16* row = base + (size_t)idx[col * 16] * 128;
#pragma unroll
                for (int j = 0; j < 4; j++) {
                    bf16x8 v = *(const bf16x8*)(row + j * 8);
#pragma unroll
                    for (int u = 0; u < 8; u++) spr[j * 8 + u] = (float)v[u];
                }
            }
            for (int k = 1; k < n; k++) {
                const __bf16* row = base + (size_t)idx[col * 16 + k] * 128;
#pragma unroll
                for (int j = 0; j < 4; j++) {
                    bf16x8 v = *(const bf16x8*)(row + j * 8);
#pragma unroll
                    for (int u = 0; u < 8; u++) spr[j * 8 + u] += (float)v[u];
                }
            }
        }
        __syncthreads();   // sp ready
        // ---- store: waves owning this column half write their tile
        if ((wid >> 1) == half) {
#pragma unroll
            for (int i = 0; i < 4; i++) {
                int gm = tM + wm2 + i * 16 + quad4;
#pragma unroll
                for (int j = 0; j < 4; j++) {
                    int gn = tN + half * 64 + j * 16 + l15;
                    int colL = j * 16 + l15;          // 0..63 within half
#pragma unroll
                    for (int r = 0; r < 4; r++) {
                        int c = wm2 + i * 16 + quad4 + r;   // channel 0..127
                        float v = acc[i][j][r];
                        float pw = p3l[c];
                        float y = (v >= 0.f) ? v : v * pw;
                        y = (y - PM) * PIS;
                        out[(size_t)(gm + r) * 4096 + gn] = sp[colL * 129 + c] * RHALF + y * RHALF;
                    }
                }
            }
        }
    }
}

// ---------------------------------------------------------------- launch
extern "C" void kernel_launch(void* const* d_in, const int* in_sizes, int n_in,
                              void* d_out, int out_size, void* d_ws, size_t ws_size,
                              hipStream_t stream) {
    (void)in_sizes; (void)n_in; (void)out_size;
    const float* x    = (const float*)d_in[0];
    const float* conn = (const float*)d_in[1];
    const float* w1   = (const float*)d_in[2];
    const float* b1   = (const float*)d_in[3];
    const float* p1   = (const float*)d_in[4];
    const float* w2   = (const float*)d_in[5];
    const float* b2   = (const float*)d_in[6];
    const float* p2   = (const float*)d_in[7];
    const float* wm   = (const float*)d_in[8];
    const float* bm   = (const float*)d_in[9];
    const float* p3   = (const float*)d_in[10];
    const float* wsw  = (const float*)d_in[11];
    const float* bs   = (const float*)d_in[12];
    float* out = (float*)d_out;

    char* ws = (char*)d_ws;
    __bf16* h3  = (__bf16*)(ws);                          // 33,554,432 B
    __bf16* s_t = (__bf16*)(ws + 33554432);               // 33,554,432 B
    __bf16* W1p = (__bf16*)(ws + 67108864);               // 12,288
    __bf16* W2p = (__bf16*)(ws + 67108864 + 12288);       // 21,504
    __bf16* WMp = (__bf16*)(ws + 67108864 + 33792);       // 32,768
    __bf16* WSp = (__bf16*)(ws + 67108864 + 66560);       // 16,384
    int* idx = (int*)(ws + 67108864 + 82944);             // 262,144
    int* cnt = (int*)(ws + 67108864 + 82944 + 262144);    // 16,384
    const size_t connb_off = 67108864 + 82944 + 262144 + 16384;   // 67,470,336

    __bf16* connb;
    size_t  cstride;
    if (ws_size >= connb_off + (size_t)4096 * 8192 * 2) {
        connb = (__bf16*)(ws + connb_off);
        cstride = 8192;
    } else {
        connb = (__bf16*)const_cast<float*>(conn);
        cstride = 16384;   // bf16 row packed into first half of its fp32 row
    }

    k_prep<<<32, 256, 0, stream>>>(w1, w2, wm, wsw, W1p, W2p, WMp, WSp);
    k_cc<<<6144, 256, 0, stream>>>(conn, connb, cstride, cnt, idx,
                                   x, b1, p1, b2, p2, bm, bs,
                                   W1p, W2p, WMp, WSp, h3, s_t);
    k_gemm<<<dim3(32, 16), 256, 0, stream>>>(h3, connb, cstride, out, s_t, idx, cnt, p3);
}

// Round 11
// 460.855 us; speedup vs baseline: 1.2735x; 1.0221x over previous
//
#include <hip/hip_runtime.h>
#include <hip/hip_bf16.h>
#include <stdint.h>

using bf16x8 = __attribute__((ext_vector_type(8))) __bf16;
using bf16x4 = __attribute__((ext_vector_type(4))) __bf16;
using f32x4  = __attribute__((ext_vector_type(4))) float;

typedef const uint32_t __attribute__((address_space(1)))* gas_ptr;
typedef uint32_t __attribute__((address_space(3)))* las_ptr;

__device__ __forceinline__ void load_lds16(const void* g, void* l) {
    __builtin_amdgcn_global_load_lds((gas_ptr)g, (las_ptr)l, 16, 0, 0);
}

// cprelu post-normalization constants (PRELU_INIT = 0.25)
#define PM  0.29920671030107454f
#define PIS 1.5046096f
#define RHALF 0.70710678118654752f

#define MFMA __builtin_amdgcn_mfma_f32_16x16x32_bf16

// ---------------------------------------------------------------- k_prep
__global__ __launch_bounds__(256) void k_prep(const float* __restrict__ w1,
                                              const float* __restrict__ w2,
                                              const float* __restrict__ wm,
                                              const float* __restrict__ wsw,
                                              __bf16* __restrict__ W1p,
                                              __bf16* __restrict__ W2p,
                                              __bf16* __restrict__ WMp,
                                              __bf16* __restrict__ WSp)
{
    const int id = blockIdx.x * 256 + threadIdx.x;
    const int stride = gridDim.x * 256;
    for (int i = id; i < 96 * 64; i += stride) {
        int oc = i >> 6, ic = i & 63;
        W1p[i] = (__bf16)((oc < 83) ? w1[oc * 64 + ic] : 0.f);
    }
    for (int i = id; i < 112 * 96; i += stride) {
        int oc = i / 96, ic = i % 96;
        W2p[i] = (__bf16)((oc < 102 && ic < 83) ? w2[oc * 83 + ic] : 0.f);
    }
    for (int i = id; i < 128 * 128; i += stride) {
        int oc = i >> 7, ic = i & 127;
        WMp[i] = (__bf16)((ic < 102) ? wm[oc * 102 + ic] : 0.f);
    }
    for (int i = id; i < 128 * 64; i += stride) {
        WSp[i] = (__bf16)wsw[i];
    }
}

// ---------------------------------------------------------------- k_cc
// Fused k_conv (4096 blocks) + k_chain (2048 blocks), interleaved 2:1.
// FROZEN from r8 — this round's gemm split makes it top-5 visible so we
// finally get its counters.
__global__ __launch_bounds__(256) void k_cc(
    // conv args
    const float* __restrict__ conn, __bf16* __restrict__ cb, size_t rowstride,
    int* __restrict__ cnt, int* __restrict__ idx,
    // chain args
    const float* __restrict__ x,
    const float* __restrict__ b1, const float* __restrict__ p1,
    const float* __restrict__ b2, const float* __restrict__ p2,
    const float* __restrict__ bm, const float* __restrict__ bs,
    const __bf16* __restrict__ W1p, const __bf16* __restrict__ W2p,
    const __bf16* __restrict__ WMp, const __bf16* __restrict__ WSp,
    __bf16* __restrict__ h3, __bf16* __restrict__ s_t)
{
    __shared__ __align__(16) char pool[38528];
    const int t = threadIdx.x;
    const int bx = blockIdx.x;
    const int r3 = bx % 3;
    const int g  = bx / 3;

    if (r3 < 2) {
        // ------------------------------------------------ conv path
        const int o = 2 * g + r3;              // 0..4095
        float* wmax = (float*)pool;            // 16 B
        int*   scnt = (int*)(pool + 16);
        const float* row = conn + (size_t)o * 8192;
        float4 v[8];
        float m = -1e30f;
#pragma unroll
        for (int q = 0; q < 8; q++) {
            v[q] = *(const float4*)(row + (size_t)(q * 256 + t) * 4);
            m = fmaxf(m, fmaxf(fmaxf(v[q].x, v[q].y), fmaxf(v[q].z, v[q].w)));
        }
        __syncthreads();   // all reads drained before in-place overwrite
        __bf16* drow = cb + (size_t)o * rowstride;
#pragma unroll
        for (int q = 0; q < 8; q++) {
            bf16x4 w;
            w[0] = (__bf16)v[q].x; w[1] = (__bf16)v[q].y;
            w[2] = (__bf16)v[q].z; w[3] = (__bf16)v[q].w;
            *(bf16x4*)(drow + (size_t)(q * 256 + t) * 4) = w;
        }
#pragma unroll
        for (int off = 32; off > 0; off >>= 1) m = fmaxf(m, __shfl_down(m, off, 64));
        if ((t & 63) == 0) wmax[t >> 6] = m;
        if (t == 0) *scnt = 0;
        __syncthreads();
        const float rmax = fmaxf(fmaxf(wmax[0], wmax[1]), fmaxf(wmax[2], wmax[3]));
#pragma unroll
        for (int q = 0; q < 8; q++) {
            float vv[4] = {v[q].x, v[q].y, v[q].z, v[q].w};
#pragma unroll
            for (int e = 0; e < 4; e++) {
                if (vv[e] >= rmax) {
                    int p = atomicAdd(scnt, 1);
                    if (p < 16) idx[o * 16 + p] = (q * 256 + t) * 4 + e;
                }
            }
        }
        __syncthreads();
        if (t == 0) cnt[o] = *scnt < 16 ? *scnt : 16;
        return;
    }

    // ---------------------------------------------------- chain path
    const int b  = g >> 7;                 // 0..15
    const int p0 = (g & 127) * 64;         // 0..8128
    __bf16* buf0 = (__bf16*)pool;          // 64*136 = 17408 B
    __bf16* un   = (__bf16*)(pool + 17408);// 128*72 = 18432 B
    float*  bl   = (float*)(pool + 35840); // 672 floats = 2688 B
    __bf16* H1t  = un;                     // 64 x 104
    __bf16* OutT = un;                     // 128 x 72
    float* b1l = bl;       float* p1l = bl + 96;
    float* b2l = bl + 192; float* p2l = bl + 304;
    float* bml = bl + 416; float* bsl = bl + 544;

    const int lane = t & 63, wid = t >> 6;

    for (int i = t; i < 96; i += 256)  { b1l[i] = (i < 83)  ? b1[i] : 0.f; p1l[i] = (i < 83)  ? p1[i] : 0.f; }
    for (int i = t; i < 112; i += 256) { b2l[i] = (i < 102) ? b2[i] : 0.f; p2l[i] = (i < 102) ? p2[i] : 0.f; }
    for (int i = t; i < 128; i += 256) { bml[i] = bm[i]; bsl[i] = bs[i]; }

    {
        // vectorized x staging: float4 along positions, transpose into LDS
        const int pg = (t & 15) * 4;        // position base 0..60
        const int c0 = t >> 4;              // 0..15
#pragma unroll
        for (int it = 0; it < 4; it++) {
            int c = it * 16 + c0;
            float4 xv = *(const float4*)(x + ((size_t)b * 64 + c) * 8192 + p0 + pg);
            buf0[(pg + 0) * 72 + c] = (__bf16)xv.x;
            buf0[(pg + 1) * 72 + c] = (__bf16)xv.y;
            buf0[(pg + 2) * 72 + c] = (__bf16)xv.z;
            buf0[(pg + 3) * 72 + c] = (__bf16)xv.w;
        }
    }
    __syncthreads();

    const int quad4 = (lane >> 4) << 2;
    const int l15 = lane & 15;
    const int kg  = (lane >> 4) << 3;
    const int nt  = wid;                   // wave-owned column tile
    const int pos = nt * 16 + l15;

    // X fragment (K=64): loaded once, reused by S (8 mt) and H1 (6 mt)
    bf16x8 xb0, xb1;
    {
        const __bf16* bp = buf0 + pos * 72 + kg;
        xb0 = *(const bf16x8*)(bp);
        xb1 = *(const bf16x8*)(bp + 32);
    }

    // shortcut S = WS*X + bs -> direct global store
#pragma unroll
    for (int mt = 0; mt < 8; mt++) {
        const __bf16* wp = WSp + (mt * 16 + l15) * 64 + kg;
        f32x4 a = {0.f, 0.f, 0.f, 0.f};
        a = MFMA(*(const bf16x8*)(wp),      xb0, a, 0, 0, 0);
        a = MFMA(*(const bf16x8*)(wp + 32), xb1, a, 0, 0, 0);
        int ocb = mt * 16 + quad4;
        bf16x4 ov;
#pragma unroll
        for (int r = 0; r < 4; r++) ov[r] = (__bf16)(a[r] + bsl[ocb + r]);
        *(bf16x4*)(s_t + ((size_t)b * 8192 + p0 + pos) * 128 + ocb) = ov;
    }

    // H1 = cprelu(W1*X + b1) -> H1t
#pragma unroll
    for (int mt = 0; mt < 6; mt++) {
        const __bf16* wp = W1p + (mt * 16 + l15) * 64 + kg;
        f32x4 a = {0.f, 0.f, 0.f, 0.f};
        a = MFMA(*(const bf16x8*)(wp),      xb0, a, 0, 0, 0);
        a = MFMA(*(const bf16x8*)(wp + 32), xb1, a, 0, 0, 0);
        int ocb = mt * 16 + quad4;
        bf16x4 ov;
#pragma unroll
        for (int r = 0; r < 4; r++) {
            float v = a[r] + b1l[ocb + r];
            v = (v >= 0.f) ? v : v * p1l[ocb + r];
            ov[r] = (__bf16)((v - PM) * PIS);
        }
        *(bf16x4*)(&H1t[pos * 104 + ocb]) = ov;
    }
    __syncthreads();

    // H2 = cprelu(W2*H1 + b2) -> buf0 (Xt dead); H1 fragment loaded once
    {
        bf16x8 hb[3];
        const __bf16* bp = H1t + pos * 104 + kg;
#pragma unroll
        for (int ks = 0; ks < 3; ks++) hb[ks] = *(const bf16x8*)(bp + ks * 32);
#pragma unroll
        for (int mt = 0; mt < 7; mt++) {
            const __bf16* wp = W2p + (mt * 16 + l15) * 96 + kg;
            f32x4 a = {0.f, 0.f, 0.f, 0.f};
#pragma unroll
            for (int ks = 0; ks < 3; ks++)
                a = MFMA(*(const bf16x8*)(wp + ks * 32), hb[ks], a, 0, 0, 0);
            int ocb = mt * 16 + quad4;
            bf16x4 ov;
#pragma unroll
            for (int r = 0; r < 4; r++) {
                float v = a[r] + b2l[ocb + r];
                v = (v >= 0.f) ? v : v * p2l[ocb + r];
                ov[r] = (__bf16)((v - PM) * PIS);
            }
            *(bf16x4*)(&buf0[pos * 136 + ocb]) = ov;
        }
    }
    // zero H2 pad channels 112..127
    for (int i = t; i < 64 * 16; i += 256) {
        int pp = i >> 4, c = 112 + (i & 15);
        buf0[pp * 136 + c] = (__bf16)0.f;
    }
    __syncthreads();   // H1t reads done before OutT overwrites region

    // H3 = WM*H2 + bm -> OutT[ch][pos]; H2 fragment loaded once
    {
        bf16x8 h2b[4];
        const __bf16* bp = buf0 + pos * 136 + kg;
#pragma unroll
        for (int ks = 0; ks < 4; ks++) h2b[ks] = *(const bf16x8*)(bp + ks * 32);
#pragma unroll
        for (int mt = 0; mt < 8; mt++) {
            const __bf16* wp = WMp + (mt * 16 + l15) * 128 + kg;
            f32x4 a = {0.f, 0.f, 0.f, 0.f};
#pragma unroll
            for (int ks = 0; ks < 4; ks++)
                a = MFMA(*(const bf16x8*)(wp + ks * 32), h2b[ks], a, 0, 0, 0);
            int ocb = mt * 16 + quad4;
#pragma unroll
            for (int r = 0; r < 4; r++)
                OutT[(ocb + r) * 72 + pos] = (__bf16)(a[r] + bml[ocb + r]);
        }
    }
    __syncthreads();

    // coalesced OutT -> h3 (bf16x8 per lane, 128B per channel row)
#pragma unroll
    for (int it = 0; it < 4; it++) {
        int lin = it * 256 + t;       // 0..1023
        int ch = lin >> 3, pc = lin & 7;
        bf16x8 v = *(const bf16x8*)(OutT + ch * 72 + pc * 8);
        *(bf16x8*)(h3 + ((size_t)b * 128 + ch) * 8192 + p0 + pc * 8) = v;
    }
}

// ---------------------------------------------------------------- k_gemm
// r0-measured split-K form (151 us): C[2048,4096] = A x B^T, 128x128 tile,
// BK=64 (32KB LDS), split-K via blockIdx.z -> 1024 blocks = 4 blocks/CU =
// 16 waves/CU. The fused-epilogue variants are grid-capped at 512 blocks =
// 8 waves/CU = ~180 us (r3/r6/r8/r10 all confirm); external split-K is the
// only proven 16-wave config with acc[4][4] economics.
// XOR swizzle: 16B chunk (row, c) of a 64-elem row stored at c ^ (row & 7).
__global__ __launch_bounds__(256, 4) void k_gemm(const __bf16* __restrict__ A,
                                                 const __bf16* __restrict__ B,
                                                 size_t bstride,
                                                 float* __restrict__ C0,
                                                 float* __restrict__ C1,
                                                 int KH)
{
    __shared__ __bf16 la[128 * 64];
    __shared__ __bf16 lb[128 * 64];
    const int t = threadIdx.x;
    const int lane = t & 63;
    const int wid = t >> 6;
    const int tM = blockIdx.y * 128;
    const int tN = blockIdx.x * 128;
    const int kz = blockIdx.z;
    const int k0 = kz * KH;
    float* __restrict__ C = kz ? C1 : C0;
    const int wm2 = (wid & 1) * 64;
    const int wn2 = (wid >> 1) * 64;

    f32x4 acc[4][4];
    const f32x4 zero = {0.f, 0.f, 0.f, 0.f};
#pragma unroll
    for (int i = 0; i < 4; i++)
#pragma unroll
        for (int j = 0; j < 4; j++) acc[i][j] = zero;

    // staging: 4 issues per matrix; issue i covers rows i*32..i*32+31
    const int tr = t >> 3;                    // 0..31
    const int sc = (t & 7) ^ (tr & 7);        // swizzled global chunk
    const __bf16* pA[4];
    const __bf16* pB[4];
#pragma unroll
    for (int i = 0; i < 4; i++) {
        pA[i] = A + (size_t)(tM + i * 32 + tr) * 8192 + k0 + sc * 8;
        pB[i] = B + (size_t)(tN + i * 32 + tr) * bstride + k0 + sc * 8;
    }

    const int l15 = lane & 15;
    const int q = lane >> 4;
    int aoff[4], boff[4];
#pragma unroll
    for (int i = 0; i < 4; i++) {
        int row = wm2 + i * 16 + l15;
        aoff[i] = row * 64 + ((q ^ (row & 7)) * 8);
    }
#pragma unroll
    for (int j = 0; j < 4; j++) {
        int row = wn2 + j * 16 + l15;
        boff[j] = row * 64 + ((q ^ (row & 7)) * 8);
    }

    const int iters = KH >> 6;
    for (int it = 0; it < iters; it++) {
#pragma unroll
        for (int i = 0; i < 4; i++) load_lds16(pA[i], la + (i * 256 + t) * 8);
#pragma unroll
        for (int i = 0; i < 4; i++) load_lds16(pB[i], lb + (i * 256 + t) * 8);
#pragma unroll
        for (int i = 0; i < 4; i++) { pA[i] += 64; pB[i] += 64; }
        __syncthreads();
#pragma unroll
        for (int ks = 0; ks < 2; ks++) {
            bf16x8 af[4], bfr[4];
#pragma unroll
            for (int i = 0; i < 4; i++) af[i]  = *(const bf16x8*)(la + (aoff[i] ^ (ks << 5)));
#pragma unroll
            for (int j = 0; j < 4; j++) bfr[j] = *(const bf16x8*)(lb + (boff[j] ^ (ks << 5)));
#pragma unroll
            for (int i = 0; i < 4; i++)
#pragma unroll
                for (int j = 0; j < 4; j++)
                    acc[i][j] = MFMA(af[i], bfr[j], acc[i][j], 0, 0, 0);
        }
        __syncthreads();
    }

    const int quad4 = (lane >> 4) * 4;
#pragma unroll
    for (int i = 0; i < 4; i++) {
        int gm = tM + wm2 + i * 16 + quad4;
#pragma unroll
        for (int j = 0; j < 4; j++) {
            int gn = tN + wn2 + j * 16 + l15;
#pragma unroll
            for (int r = 0; r < 4; r++)
                C[(size_t)(gm + r) * 4096 + gn] = acc[i][j][r];
        }
    }
}

// ---------------------------------------------------------------- k_combine
__global__ __launch_bounds__(256) void k_combine(float* __restrict__ out,
                                                 const float* __restrict__ P1,
                                                 int nsplit,
                                                 const __bf16* __restrict__ s_t,
                                                 const int* __restrict__ idx,
                                                 const int* __restrict__ cnt,
                                                 const float* __restrict__ p3)
{
    __shared__ float sp[64][133];
    const int b = blockIdx.y;
    const int o0 = blockIdx.x * 64;
    const int t = threadIdx.x;

    {
        const int ol = t >> 2;
        const int part = t & 3;
        const int o = o0 + ol;
        const int n = cnt[o];
        float acc[32];
#pragma unroll
        for (int j = 0; j < 32; j++) acc[j] = 0.f;
        for (int k = 0; k < n; k++) {
            const int i = idx[o * 16 + k];
            const __bf16* row = s_t + ((size_t)b * 8192 + i) * 128 + part * 32;
#pragma unroll
            for (int j = 0; j < 32; j += 8) {
                bf16x8 v = *(const bf16x8*)(row + j);
#pragma unroll
                for (int u = 0; u < 8; u++) acc[j + u] += (float)v[u];
            }
        }
#pragma unroll
        for (int j = 0; j < 32; j++) sp[ol][part * 32 + j] = acc[j];
    }
    __syncthreads();

    if (nsplit == 2) {
        for (int rr = 0; rr < 32; rr++) {
            const int c = rr * 4 + (t >> 6);
            const int o = t & 63;
            const size_t oi = ((size_t)b * 128 + c) * 4096 + o0 + o;
            float v = out[oi] + P1[oi];
            const float pw = p3[c];
            float y = (v >= 0.f) ? v : v * pw;
            y = (y - PM) * PIS;
            out[oi] = sp[o][c] * RHALF + y * RHALF;
        }
    } else {
        for (int rr = 0; rr < 32; rr++) {
            const int c = rr * 4 + (t >> 6);
            const int o = t & 63;
            const size_t oi = ((size_t)b * 128 + c) * 4096 + o0 + o;
            float v = out[oi];
            const float pw = p3[c];
            float y = (v >= 0.f) ? v : v * pw;
            y = (y - PM) * PIS;
            out[oi] = sp[o][c] * RHALF + y * RHALF;
        }
    }
}

// ---------------------------------------------------------------- launch
extern "C" void kernel_launch(void* const* d_in, const int* in_sizes, int n_in,
                              void* d_out, int out_size, void* d_ws, size_t ws_size,
                              hipStream_t stream) {
    (void)in_sizes; (void)n_in; (void)out_size;
    const float* x    = (const float*)d_in[0];
    const float* conn = (const float*)d_in[1];
    const float* w1   = (const float*)d_in[2];
    const float* b1   = (const float*)d_in[3];
    const float* p1   = (const float*)d_in[4];
    const float* w2   = (const float*)d_in[5];
    const float* b2   = (const float*)d_in[6];
    const float* p2   = (const float*)d_in[7];
    const float* wm   = (const float*)d_in[8];
    const float* bm   = (const float*)d_in[9];
    const float* p3   = (const float*)d_in[10];
    const float* wsw  = (const float*)d_in[11];
    const float* bs   = (const float*)d_in[12];
    float* out = (float*)d_out;

    char* ws = (char*)d_ws;
    __bf16* h3  = (__bf16*)(ws);                          // 33,554,432 B
    __bf16* s_t = (__bf16*)(ws + 33554432);               // 33,554,432 B
    __bf16* W1p = (__bf16*)(ws + 67108864);               // 12,288
    __bf16* W2p = (__bf16*)(ws + 67108864 + 12288);       // 21,504
    __bf16* WMp = (__bf16*)(ws + 67108864 + 33792);       // 32,768
    __bf16* WSp = (__bf16*)(ws + 67108864 + 66560);       // 16,384
    int* idx = (int*)(ws + 67108864 + 82944);             // 262,144
    int* cnt = (int*)(ws + 67108864 + 82944 + 262144);    // 16,384
    const size_t p1_off    = 67108864 + 82944 + 262144 + 16384;   // 67,470,336
    float* Pk1 = (float*)(ws + p1_off);                   // 33,554,432
    const size_t connb_off = p1_off + 33554432;           // 101,024,768

    __bf16* connb;
    size_t  cstride;
    if (ws_size >= connb_off + (size_t)4096 * 8192 * 2) {
        connb = (__bf16*)(ws + connb_off);
        cstride = 8192;
    } else {
        connb = (__bf16*)const_cast<float*>(conn);
        cstride = 16384;   // bf16 row packed into first half of its fp32 row
    }
    const int nsplit = (ws_size >= p1_off + 33554432) ? 2 : 1;
    const int KH = 8192 / nsplit;

    k_prep<<<32, 256, 0, stream>>>(w1, w2, wm, wsw, W1p, W2p, WMp, WSp);
    k_cc<<<6144, 256, 0, stream>>>(conn, connb, cstride, cnt, idx,
                                   x, b1, p1, b2, p2, bm, bs,
                                   W1p, W2p, WMp, WSp, h3, s_t);
    k_gemm<<<dim3(4096 / 128, 2048 / 128, nsplit), 256, 0, stream>>>(h3, connb, cstride,
                                                                     out, Pk1, KH);
    k_combine<<<dim3(4096 / 64, 16), 256, 0, stream>>>(out, Pk1, nsplit, s_t, idx, cnt, p3);
}